// Round 1
// 136.981 us; speedup vs baseline: 1.1470x; 1.1470x over previous
//
#include <hip/hip_runtime.h>
#include <cstdint>

#define KDIM 128
#define BATCH 131072
#define LDH 136    // bf16 LDS row stride for H: 272 B/row, 16B-aligned, spreads banks

typedef __attribute__((ext_vector_type(8))) short short8x;          // MFMA A/B frag
typedef __attribute__((ext_vector_type(4))) float float4x;          // MFMA C/D frag
typedef __attribute__((ext_vector_type(4))) unsigned int uint4x;

// pack two fp32 -> bf16x2 dword, round-half-up (1 add per elem + 1 v_perm)
__device__ __forceinline__ unsigned int pk_bf16(float a, float b) {
    unsigned int ua = __float_as_uint(a) + 0x8000u;
    unsigned int ub = __float_as_uint(b) + 0x8000u;
    return __builtin_amdgcn_perm(ub, ua, 0x07060302u);  // {hi16(b), hi16(a)}
}

__device__ __forceinline__ unsigned short f2bf(float f) {   // RNE, prep kernel only
    unsigned int u = __float_as_uint(f);
    u += 0x7FFFu + ((u >> 16) & 1u);
    return (unsigned short)(u >> 16);
}

// clamped Pade tanh: err<=0.025 abs; y-sensitivity 0.05 -> <1.3e-3 in y. No transcendental.
__device__ __forceinline__ float tanh_pade(float v) {
    float z  = fminf(fmaxf(v, -4.0f), 4.0f);
    float z2 = z * z;
    float num = z * (27.0f + z2);
    float den = fmaf(z2, 9.0f, 27.0f);
    return num * __frcp_rn(den);
}

// direct-to-LDS 16B async copy: LDS dest = (wave-uniform base) + lane*16
__device__ __forceinline__ void gload_lds16(const void* g, void* l) {
    __builtin_amdgcn_global_load_lds(
        (const __attribute__((address_space(1))) void*)g,
        (__attribute__((address_space(3))) void*)l, 16, 0, 0);
}

// Repack W[k][n] fp32 -> fragment-lane-major bf16 so each per-(nt,ks) A-frag load in
// the main kernel is ONE fully-coalesced 1KB global_load_dwordx4 (lane i -> base+i*16):
//   Wf[((nt*4+ks)*64 + lane)*8 + j] = W[ks*32 + (lane>>4)*8 + j][nt*16 + (lane&15)]
__global__ void prep_weights(const float* __restrict__ W1, const float* __restrict__ W2,
                             unsigned short* __restrict__ W1f, unsigned short* __restrict__ W2f) {
    int idx  = blockIdx.x * 256 + threadIdx.x;      // 0..16383
    int j    = idx & 7;
    int lane = (idx >> 3) & 63;
    int fr   = idx >> 9;                            // nt*4 + ks
    int ks   = fr & 3, nt = fr >> 2;
    int k = ks * 32 + (lane >> 4) * 8 + j;
    int n = nt * 16 + (lane & 15);
    W1f[idx] = f2bf(W1[k * 128 + n]);
    W2f[idx] = f2bf(W2[k * 128 + n]);
}

// Wave-private, barrier-free. M=16 rows/wave. All global traffic coalesced:
//  - x staged via global_load_lds (no VGPR landing, 8 x 1KB contiguous per wave)
//  - W frags are 1KB contiguous loads (repacked layout)
//  - y written back in-place into the x LDS region, then stored as 8 x 1KB contiguous
__global__ __launch_bounds__(256, 3) void koopman_main(
        const float* __restrict__ x, const float* __restrict__ b1,
        const float* __restrict__ b2, const unsigned short* __restrict__ W1f,
        const unsigned short* __restrict__ W2f, float* __restrict__ y) {
    __shared__ __align__(16) float          XY[4][2048];   // x stage / y stage, 8KB/wave
    __shared__ __align__(16) unsigned short Hs[4][2176];   // H bf16, 4.25KB/wave

    const int tid  = threadIdx.x;
    const int lane = tid & 63;
    const int wave = tid >> 6;
    const int l15  = lane & 15;
    const int quad = lane >> 4;
    const int row0 = blockIdx.x * 64 + wave * 16;

    float*          Xw = XY[wave];
    unsigned short* Hw = Hs[wave];

    // ---- phase 1: stage 16 rows x 512B of x, fully coalesced, all 8 loads in flight ----
    #pragma unroll
    for (int c = 0; c < 8; ++c) {
        const float* src = x + (size_t)(row0 + c * 2 + (lane >> 5)) * KDIM + (lane & 31) * 4;
        gload_lds16(src, &Xw[c * 256]);     // LDS row-major copy: row r at floats [r*128, +128)
    }
    asm volatile("s_waitcnt vmcnt(0)" ::: "memory");

    // ---- phase 2: build bf16 B-frags (X^T): lane needs row l15, floats ks*32+quad*8..+8 ----
    short8x xf[4];
    #pragma unroll
    for (int ks = 0; ks < 4; ++ks) {
        float4 v0 = *(const float4*)&Xw[l15 * 128 + ks * 32 + quad * 8];
        float4 v1 = *(const float4*)&Xw[l15 * 128 + ks * 32 + quad * 8 + 4];
        uint4x u;
        u[0] = pk_bf16(v0.x, v0.y);
        u[1] = pk_bf16(v0.z, v0.w);
        u[2] = pk_bf16(v1.x, v1.y);
        u[3] = pk_bf16(v1.z, v1.w);
        xf[ks] = __builtin_bit_cast(short8x, u);
    }

    // ---- matmul 1: D[col][row] = W1^T @ X^T ; W frags are coalesced 1KB loads ----
    float4x acc[8];
    #pragma unroll
    for (int nt = 0; nt < 8; ++nt) acc[nt] = (float4x){0.f, 0.f, 0.f, 0.f};
    #pragma unroll
    for (int ks = 0; ks < 4; ++ks) {
        #pragma unroll
        for (int nt = 0; nt < 8; ++nt) {
            short8x w = *(const short8x*)&W1f[((nt * 4 + ks) * 64 + lane) * 8];
            acc[nt] = __builtin_amdgcn_mfma_f32_16x16x32_bf16(w, xf[ks], acc[nt], 0, 0, 0);
        }
    }

    // ---- bias + tanh -> packed b64 LDS writes (lane owns row l15, cols nt*16+quad*4..+3) ----
    #pragma unroll
    for (int nt = 0; nt < 8; ++nt) {
        float4 bb = *(const float4*)&b1[nt * 16 + quad * 4];
        float4x v = acc[nt];
        float t0 = tanh_pade(v[0] + bb.x);
        float t1 = tanh_pade(v[1] + bb.y);
        float t2 = tanh_pade(v[2] + bb.z);
        float t3 = tanh_pade(v[3] + bb.w);
        uint2 d;
        d.x = pk_bf16(t0, t1);
        d.y = pk_bf16(t2, t3);
        *(uint2*)&Hw[l15 * LDH + nt * 16 + quad * 4] = d;
    }

    // ---- matmul 2: D[col][row] = W2^T @ H^T ----
    float4x acc2[8];
    #pragma unroll
    for (int nt = 0; nt < 8; ++nt) acc2[nt] = (float4x){0.f, 0.f, 0.f, 0.f};
    #pragma unroll
    for (int ks = 0; ks < 4; ++ks) {
        short8x hf = *(const short8x*)&Hw[l15 * LDH + ks * 32 + quad * 8];
        #pragma unroll
        for (int nt = 0; nt < 8; ++nt) {
            short8x w = *(const short8x*)&W2f[((nt * 4 + ks) * 64 + lane) * 8];
            acc2[nt] = __builtin_amdgcn_mfma_f32_16x16x32_bf16(w, hf, acc2[nt], 0, 0, 0);
        }
    }

    // ---- fused epilogue, in-place in LDS: read x slot, compute, write y to same slot ----
    #pragma unroll
    for (int nt = 0; nt < 8; ++nt) {
        float4 bv = *(const float4*)&b2[nt * 16 + quad * 4];
        float4 xv = *(const float4*)&Xw[l15 * 128 + nt * 16 + quad * 4];
        float4x v = acc2[nt];
        float4 out;
        {
            float tm = 0.01f * (v[0] + bv.x);
            float tw = 0.01f * (v[1] + bv.y);
            float tm2 = tm * tm, tw2 = tw * tw;
            float ex = fmaf(tm2, fmaf(tm, 0.16666667f, 0.5f), 1.0f + tm);
            float s  = tw * fmaf(tw2, -0.16666667f, 1.0f);
            float c  = fmaf(tw2, -0.5f, 1.0f);
            out.x = ex * fmaf(c, xv.x, -s * xv.y);
            out.y = ex * fmaf(s, xv.x,  c * xv.y);
        }
        {
            float tm = 0.01f * (v[2] + bv.z);
            float tw = 0.01f * (v[3] + bv.w);
            float tm2 = tm * tm, tw2 = tw * tw;
            float ex = fmaf(tm2, fmaf(tm, 0.16666667f, 0.5f), 1.0f + tm);
            float s  = tw * fmaf(tw2, -0.16666667f, 1.0f);
            float c  = fmaf(tw2, -0.5f, 1.0f);
            out.z = ex * fmaf(c, xv.z, -s * xv.w);
            out.w = ex * fmaf(s, xv.z,  c * xv.w);
        }
        *(float4*)&Xw[l15 * 128 + nt * 16 + quad * 4] = out;
    }

    // ---- phase 7: fully coalesced y store, 8 x 1KB contiguous per wave ----
    #pragma unroll
    for (int c = 0; c < 8; ++c) {
        float4 v = *(const float4*)&Xw[c * 256 + lane * 4];
        float* dst = y + (size_t)(row0 + c * 2 + (lane >> 5)) * KDIM + (lane & 31) * 4;
        *(float4*)dst = v;
    }
}

extern "C" void kernel_launch(void* const* d_in, const int* in_sizes, int n_in,
                              void* d_out, int out_size, void* d_ws, size_t ws_size,
                              hipStream_t stream) {
    const float* x  = (const float*)d_in[0];
    const float* W1 = (const float*)d_in[1];
    const float* b1 = (const float*)d_in[2];
    const float* W2 = (const float*)d_in[3];
    const float* b2 = (const float*)d_in[4];
    float* y = (float*)d_out;

    unsigned short* W1f = (unsigned short*)d_ws;
    unsigned short* W2f = W1f + 128 * 128;

    prep_weights<<<64, 256, 0, stream>>>(W1, W2, W1f, W2f);
    koopman_main<<<BATCH / 64, 256, 0, stream>>>(x, b1, b2, W1f, W2f, y);
}

// Round 2
// 136.106 us; speedup vs baseline: 1.1543x; 1.0064x over previous
//
#include <hip/hip_runtime.h>
#include <cstdint>

#define KDIM 128
#define BATCH 131072
#define LDH 136    // bf16 LDS row stride for H: 272 B/row, 16B-aligned, spreads banks

typedef __attribute__((ext_vector_type(8))) short short8x;          // MFMA A/B frag
typedef __attribute__((ext_vector_type(4))) float float4x;          // MFMA C/D frag
typedef __attribute__((ext_vector_type(4))) unsigned int uint4x;

// pack two fp32 -> bf16x2 dword, round-half-up (1 add per elem + 1 v_perm)
__device__ __forceinline__ unsigned int pk_bf16(float a, float b) {
    unsigned int ua = __float_as_uint(a) + 0x8000u;
    unsigned int ub = __float_as_uint(b) + 0x8000u;
    return __builtin_amdgcn_perm(ub, ua, 0x07060302u);  // {hi16(b), hi16(a)}
}

__device__ __forceinline__ unsigned short f2bf(float f) {   // RNE, prep kernel only
    unsigned int u = __float_as_uint(f);
    u += 0x7FFFu + ((u >> 16) & 1u);
    return (unsigned short)(u >> 16);
}

// clamped Pade tanh: err<=0.025 abs; y-sensitivity 0.05 -> <1.3e-3 in y. No transcendental.
__device__ __forceinline__ float tanh_pade(float v) {
    float z  = fminf(fmaxf(v, -4.0f), 4.0f);
    float z2 = z * z;
    float num = z * (27.0f + z2);
    float den = fmaf(z2, 9.0f, 27.0f);
    return num * __frcp_rn(den);
}

// direct-to-LDS 16B async copy: LDS dest = (wave-uniform base) + lane*16
__device__ __forceinline__ void gload_lds16(const void* g, void* l) {
    __builtin_amdgcn_global_load_lds(
        (const __attribute__((address_space(1))) void*)g,
        (__attribute__((address_space(3))) void*)l, 16, 0, 0);
}

// Xw swizzle: LDS slot (row, s) holds global slot s ^ (row&7). 16B slots, 32 slots/row.
// Breaks the 512B power-of-2 row stride (was 16-way bank conflict on all row-indexed
// b128 accesses). XOR permutes slots only within each 128B line -> global stays coalesced.
__device__ __forceinline__ int xsw(int row, int slot) {     // -> float index into Xw
    return row * 128 + ((slot ^ (row & 7)) << 2);
}

// Repack W[k][n] fp32 -> fragment-lane-major bf16 so each per-(nt,ks) A-frag load in
// the main kernel is ONE fully-coalesced 1KB global_load_dwordx4 (lane i -> base+i*16):
//   Wf[((nt*4+ks)*64 + lane)*8 + j] = W[ks*32 + (lane>>4)*8 + j][nt*16 + (lane&15)]
__global__ void prep_weights(const float* __restrict__ W1, const float* __restrict__ W2,
                             unsigned short* __restrict__ W1f, unsigned short* __restrict__ W2f) {
    int idx  = blockIdx.x * 256 + threadIdx.x;      // 0..16383
    int j    = idx & 7;
    int lane = (idx >> 3) & 63;
    int fr   = idx >> 9;                            // nt*4 + ks
    int ks   = fr & 3, nt = fr >> 2;
    int k = ks * 32 + (lane >> 4) * 8 + j;
    int n = nt * 16 + (lane & 15);
    W1f[idx] = f2bf(W1[k * 128 + n]);
    W2f[idx] = f2bf(W2[k * 128 + n]);
}

// Wave-private, barrier-free. M=16 rows/wave. All global traffic coalesced:
//  - x staged via global_load_lds (no VGPR landing, 8 x 1KB contiguous per wave),
//    source pre-swizzled so the linear LDS write produces the bank-swizzled layout
//  - W frags are 1KB contiguous loads (repacked layout)
//  - y written back in-place into the x LDS region, then stored as 8 x 1KB contiguous
__global__ __launch_bounds__(256, 3) void koopman_main(
        const float* __restrict__ x, const float* __restrict__ b1,
        const float* __restrict__ b2, const unsigned short* __restrict__ W1f,
        const unsigned short* __restrict__ W2f, float* __restrict__ y) {
    __shared__ __align__(16) float          XY[4][2048];   // x stage / y stage, 8KB/wave
    __shared__ __align__(16) unsigned short Hs[4][2176];   // H bf16, 4.25KB/wave

    const int tid  = threadIdx.x;
    const int lane = tid & 63;
    const int wave = tid >> 6;
    const int l15  = lane & 15;
    const int quad = lane >> 4;
    const int row0 = blockIdx.x * 64 + wave * 16;

    float*          Xw = XY[wave];
    unsigned short* Hw = Hs[wave];

    // ---- phase 1: stage 16 rows x 512B of x, fully coalesced, all 8 loads in flight.
    //      Source is slot-swizzled per lane; LDS dest stays linear (HW: base + lane*16).
    #pragma unroll
    for (int c = 0; c < 8; ++c) {
        int r = c * 2 + (lane >> 5);                 // row within wave tile
        int s = (lane & 31) ^ (r & 7);               // swizzled source slot
        const float* src = x + (size_t)(row0 + r) * KDIM + s * 4;
        gload_lds16(src, &Xw[c * 256]);              // lands at slot (lane&31) of row r
    }
    asm volatile("s_waitcnt vmcnt(0)" ::: "memory");

    // ---- phase 2: build bf16 B-frags (X^T): lane reads row l15, slots ks*8+quad*2, +1 ----
    short8x xf[4];
    #pragma unroll
    for (int ks = 0; ks < 4; ++ks) {
        int t0 = ks * 8 + quad * 2;
        float4 v0 = *(const float4*)&Xw[xsw(l15, t0)];
        float4 v1 = *(const float4*)&Xw[xsw(l15, t0 + 1)];
        uint4x u;
        u[0] = pk_bf16(v0.x, v0.y);
        u[1] = pk_bf16(v0.z, v0.w);
        u[2] = pk_bf16(v1.x, v1.y);
        u[3] = pk_bf16(v1.z, v1.w);
        xf[ks] = __builtin_bit_cast(short8x, u);
    }

    // ---- matmul 1: D[col][row] = W1^T @ X^T ; W frags are coalesced 1KB loads ----
    float4x acc[8];
    #pragma unroll
    for (int nt = 0; nt < 8; ++nt) acc[nt] = (float4x){0.f, 0.f, 0.f, 0.f};
    #pragma unroll
    for (int ks = 0; ks < 4; ++ks) {
        #pragma unroll
        for (int nt = 0; nt < 8; ++nt) {
            short8x w = *(const short8x*)&W1f[((nt * 4 + ks) * 64 + lane) * 8];
            acc[nt] = __builtin_amdgcn_mfma_f32_16x16x32_bf16(w, xf[ks], acc[nt], 0, 0, 0);
        }
    }

    // ---- bias + tanh -> packed b64 LDS writes (lane owns row l15, cols nt*16+quad*4..+3) ----
    #pragma unroll
    for (int nt = 0; nt < 8; ++nt) {
        float4 bb = *(const float4*)&b1[nt * 16 + quad * 4];
        float4x v = acc[nt];
        float t0 = tanh_pade(v[0] + bb.x);
        float t1 = tanh_pade(v[1] + bb.y);
        float t2 = tanh_pade(v[2] + bb.z);
        float t3 = tanh_pade(v[3] + bb.w);
        uint2 d;
        d.x = pk_bf16(t0, t1);
        d.y = pk_bf16(t2, t3);
        *(uint2*)&Hw[l15 * LDH + nt * 16 + quad * 4] = d;
    }

    // ---- matmul 2: D[col][row] = W2^T @ H^T ----
    float4x acc2[8];
    #pragma unroll
    for (int nt = 0; nt < 8; ++nt) acc2[nt] = (float4x){0.f, 0.f, 0.f, 0.f};
    #pragma unroll
    for (int ks = 0; ks < 4; ++ks) {
        short8x hf = *(const short8x*)&Hw[l15 * LDH + ks * 32 + quad * 8];
        #pragma unroll
        for (int nt = 0; nt < 8; ++nt) {
            short8x w = *(const short8x*)&W2f[((nt * 4 + ks) * 64 + lane) * 8];
            acc2[nt] = __builtin_amdgcn_mfma_f32_16x16x32_bf16(w, hf, acc2[nt], 0, 0, 0);
        }
    }

    // ---- fused epilogue, in-place in LDS: read x slot, compute, write y to same slot ----
    #pragma unroll
    for (int nt = 0; nt < 8; ++nt) {
        float4 bv = *(const float4*)&b2[nt * 16 + quad * 4];
        int off = xsw(l15, nt * 4 + quad);
        float4 xv = *(const float4*)&Xw[off];
        float4x v = acc2[nt];
        float4 out;
        {
            float tm = 0.01f * (v[0] + bv.x);
            float tw = 0.01f * (v[1] + bv.y);
            float tm2 = tm * tm, tw2 = tw * tw;
            float ex = fmaf(tm2, fmaf(tm, 0.16666667f, 0.5f), 1.0f + tm);
            float s  = tw * fmaf(tw2, -0.16666667f, 1.0f);
            float c  = fmaf(tw2, -0.5f, 1.0f);
            out.x = ex * fmaf(c, xv.x, -s * xv.y);
            out.y = ex * fmaf(s, xv.x,  c * xv.y);
        }
        {
            float tm = 0.01f * (v[2] + bv.z);
            float tw = 0.01f * (v[3] + bv.w);
            float tm2 = tm * tm, tw2 = tw * tw;
            float ex = fmaf(tm2, fmaf(tm, 0.16666667f, 0.5f), 1.0f + tm);
            float s  = tw * fmaf(tw2, -0.16666667f, 1.0f);
            float c  = fmaf(tw2, -0.5f, 1.0f);
            out.z = ex * fmaf(c, xv.z, -s * xv.w);
            out.w = ex * fmaf(s, xv.z,  c * xv.w);
        }
        *(float4*)&Xw[off] = out;
    }

    // ---- phase 7: y store. LDS read is linear (conflict-free); global dst carries the
    //      inverse slot swizzle -> still one contiguous permuted 512B segment per 32 lanes.
    #pragma unroll
    for (int c = 0; c < 8; ++c) {
        int r = c * 2 + (lane >> 5);
        int sp = (lane & 31) ^ (r & 7);
        float4 v = *(const float4*)&Xw[c * 256 + lane * 4];
        float* dst = y + (size_t)(row0 + r) * KDIM + sp * 4;
        *(float4*)dst = v;
    }
}

extern "C" void kernel_launch(void* const* d_in, const int* in_sizes, int n_in,
                              void* d_out, int out_size, void* d_ws, size_t ws_size,
                              hipStream_t stream) {
    const float* x  = (const float*)d_in[0];
    const float* W1 = (const float*)d_in[1];
    const float* b1 = (const float*)d_in[2];
    const float* W2 = (const float*)d_in[3];
    const float* b2 = (const float*)d_in[4];
    float* y = (float*)d_out;

    unsigned short* W1f = (unsigned short*)d_ws;
    unsigned short* W2f = W1f + 128 * 128;

    prep_weights<<<64, 256, 0, stream>>>(W1, W2, W1f, W2f);
    koopman_main<<<BATCH / 64, 256, 0, stream>>>(x, b1, b2, W1f, W2f, y);
}

// Round 3
// 134.509 us; speedup vs baseline: 1.1680x; 1.0119x over previous
//
#include <hip/hip_runtime.h>
#include <cstdint>

#define KDIM 128
#define BATCH 131072

typedef __attribute__((ext_vector_type(8))) short short8x;          // MFMA A/B frag
typedef __attribute__((ext_vector_type(4))) float float4x;          // MFMA C/D frag
typedef __attribute__((ext_vector_type(4))) unsigned int uint4x;

// pack two fp32 -> bf16x2 dword, round-half-up (1 add per elem + 1 v_perm)
__device__ __forceinline__ unsigned int pk_bf16(float a, float b) {
    unsigned int ua = __float_as_uint(a) + 0x8000u;
    unsigned int ub = __float_as_uint(b) + 0x8000u;
    return __builtin_amdgcn_perm(ub, ua, 0x07060302u);  // {hi16(b), hi16(a)}
}

__device__ __forceinline__ unsigned short f2bf(float f) {   // RNE, prep kernel only
    unsigned int u = __float_as_uint(f);
    u += 0x7FFFu + ((u >> 16) & 1u);
    return (unsigned short)(u >> 16);
}

// clamped Pade tanh: err<=0.025 abs; y-sensitivity 0.05 -> <1.3e-3 in y. No transcendental.
__device__ __forceinline__ float tanh_pade(float v) {
    float z  = fminf(fmaxf(v, -4.0f), 4.0f);
    float z2 = z * z;
    float num = z * (27.0f + z2);
    float den = fmaf(z2, 9.0f, 27.0f);
    return num * __frcp_rn(den);
}

// direct-to-LDS 16B async copy: LDS dest = (wave-uniform base) + lane*16
__device__ __forceinline__ void gload_lds16(const void* g, void* l) {
    __builtin_amdgcn_global_load_lds(
        (const __attribute__((address_space(1))) void*)g,
        (__attribute__((address_space(3))) void*)l, 16, 0, 0);
}

// Repack W[k][n] fp32 -> fragment-lane-major bf16 so each per-(nt,ks) A-frag load in
// the main kernel is ONE fully-coalesced 1KB global_load_dwordx4 (lane i -> base+i*16):
//   Wf[((nt*4+ks)*64 + lane)*8 + j] = W[ks*32 + (lane>>4)*8 + j][nt*16 + (lane&15)]
__global__ void prep_weights(const float* __restrict__ W1, const float* __restrict__ W2,
                             unsigned short* __restrict__ W1f, unsigned short* __restrict__ W2f) {
    int idx  = blockIdx.x * 256 + threadIdx.x;      // 0..16383
    int j    = idx & 7;
    int lane = (idx >> 3) & 63;
    int fr   = idx >> 9;                            // nt*4 + ks
    int ks   = fr & 3, nt = fr >> 2;
    int k = ks * 32 + (lane >> 4) * 8 + j;
    int n = nt * 16 + (lane & 15);
    W1f[idx] = f2bf(W1[k * 128 + n]);
    W2f[idx] = f2bf(W2[k * 128 + n]);
}

// Wave-private, barrier-free. M=32 rows/wave (W-frag loads amortized 2x vs M=16).
//  - x staged via global_load_lds (16 x 1KB coalesced), source slot-swizzled
//  - W frags: rolling 8-frag register double-buffer, prefetched across phases
//  - H matmul1->matmul2 handoff fully in-register via quad shuffles (no H LDS)
//  - y written back in-place into the x LDS region, stored as 16 x 1KB contiguous
__global__ __launch_bounds__(256, 2) void koopman_main(
        const float* __restrict__ x, const float* __restrict__ b1,
        const float* __restrict__ b2, const unsigned short* __restrict__ W1f,
        const unsigned short* __restrict__ W2f, float* __restrict__ y) {
    __shared__ __align__(16) float XY[4][4096];   // 16KB/wave x-stage / y-stage = 64KB/block

    const int tid  = threadIdx.x;
    const int lane = tid & 63;
    const int wave = tid >> 6;
    const int l15  = lane & 15;
    const int quad = lane >> 4;
    const int row0 = blockIdx.x * 128 + wave * 32;

    float* Xw = XY[wave];

    // ---- phase 1: stage 32 rows x 512B of x, fully coalesced, all 16 loads in flight.
    //      Source is slot-swizzled per lane; LDS dest stays linear (HW: base + lane*16).
    #pragma unroll
    for (int c = 0; c < 16; ++c) {
        int r = c * 2 + (lane >> 5);                 // row within wave tile
        int s = (lane & 31) ^ (r & 7);               // swizzled source slot
        gload_lds16(x + (size_t)(row0 + r) * KDIM + s * 4, &Xw[c * 256]);
    }

    // ---- W1 ks=0 frag prefetch: issued before the x-wait, covered by the same stall ----
    short8x wf[8];
    #pragma unroll
    for (int nt = 0; nt < 8; ++nt)
        wf[nt] = *(const short8x*)&W1f[((nt * 4 + 0) * 64 + lane) * 8];

    asm volatile("s_waitcnt vmcnt(0)" ::: "memory");

    // ---- phase 2: build bf16 B-frags (X^T), rows 16h+l15, slots ks*8+quad*2, +1 ----
    short8x xf[2][4];
    #pragma unroll
    for (int h = 0; h < 2; ++h) {
        int rr = 16 * h + l15;
        #pragma unroll
        for (int ks = 0; ks < 4; ++ks) {
            int t0 = ks * 8 + quad * 2;
            float4 v0 = *(const float4*)&Xw[rr * 128 + (((t0    ) ^ (rr & 7)) << 2)];
            float4 v1 = *(const float4*)&Xw[rr * 128 + (((t0 + 1) ^ (rr & 7)) << 2)];
            uint4x u;
            u[0] = pk_bf16(v0.x, v0.y);
            u[1] = pk_bf16(v0.z, v0.w);
            u[2] = pk_bf16(v1.x, v1.y);
            u[3] = pk_bf16(v1.z, v1.w);
            xf[h][ks] = __builtin_bit_cast(short8x, u);
        }
    }

    // ---- matmul 1: D[n][m] = W1^T @ X^T ; rolling W buffer, each frag feeds 2 MFMAs ----
    float4x acc[2][8];
    #pragma unroll
    for (int h = 0; h < 2; ++h)
        #pragma unroll
        for (int nt = 0; nt < 8; ++nt) acc[h][nt] = (float4x){0.f, 0.f, 0.f, 0.f};
    #pragma unroll
    for (int ks = 0; ks < 4; ++ks) {
        short8x wn[8];
        #pragma unroll
        for (int nt = 0; nt < 8; ++nt) {
            const unsigned short* src = (ks < 3)
                ? &W1f[((nt * 4 + ks + 1) * 64 + lane) * 8]
                : &W2f[((nt * 4 + 0) * 64 + lane) * 8];   // prefetch W2 ks0 under tanh
            wn[nt] = *(const short8x*)src;
        }
        #pragma unroll
        for (int nt = 0; nt < 8; ++nt) {
            acc[0][nt] = __builtin_amdgcn_mfma_f32_16x16x32_bf16(wf[nt], xf[0][ks], acc[0][nt], 0, 0, 0);
            acc[1][nt] = __builtin_amdgcn_mfma_f32_16x16x32_bf16(wf[nt], xf[1][ks], acc[1][nt], 0, 0, 0);
        }
        #pragma unroll
        for (int nt = 0; nt < 8; ++nt) wf[nt] = wn[nt];
    }

    // ---- bias + tanh -> packed bf16 pairs, kept in registers.
    //      lane(l15,q) holds d[h][nt] = H[16h+l15][16nt+4q + {0,1 | 2,3}] ----
    uint2 d[2][8];
    #pragma unroll
    for (int nt = 0; nt < 8; ++nt) {
        float4 bb = *(const float4*)&b1[nt * 16 + quad * 4];
        #pragma unroll
        for (int h = 0; h < 2; ++h) {
            float4x v = acc[h][nt];
            float t0 = tanh_pade(v[0] + bb.x);
            float t1 = tanh_pade(v[1] + bb.y);
            float t2 = tanh_pade(v[2] + bb.z);
            float t3 = tanh_pade(v[3] + bb.w);
            d[h][nt].x = pk_bf16(t0, t1);
            d[h][nt].y = pk_bf16(t2, t3);
        }
    }

    // ---- matmul 2: B-frags built in-register via quad shuffles.
    //      Target lane(a=bit4, b=bit5) dword w <- lane l15+16*(w>>1)+32a, d[2ks+b], half w&1.
    const int  Lx  = l15 + ((lane & 16) << 1);   // l15 + 32a
    const bool bhi = (lane & 32) != 0;
    float4x acc2[2][8];
    #pragma unroll
    for (int h = 0; h < 2; ++h)
        #pragma unroll
        for (int nt = 0; nt < 8; ++nt) acc2[h][nt] = (float4x){0.f, 0.f, 0.f, 0.f};
    #pragma unroll
    for (int ks = 0; ks < 4; ++ks) {
        short8x wn[8];
        if (ks < 3) {
            #pragma unroll
            for (int nt = 0; nt < 8; ++nt)
                wn[nt] = *(const short8x*)&W2f[((nt * 4 + ks + 1) * 64 + lane) * 8];
        }
        short8x hf[2];
        #pragma unroll
        for (int h = 0; h < 2; ++h) {
            uint2 lo = d[h][2 * ks], hi = d[h][2 * ks + 1];
            unsigned s0 = (unsigned)__shfl((int)lo.x, Lx);
            unsigned s1 = (unsigned)__shfl((int)lo.y, Lx);
            unsigned s2 = (unsigned)__shfl((int)lo.x, Lx + 16);
            unsigned s3 = (unsigned)__shfl((int)lo.y, Lx + 16);
            unsigned t0 = (unsigned)__shfl((int)hi.x, Lx);
            unsigned t1 = (unsigned)__shfl((int)hi.y, Lx);
            unsigned t2 = (unsigned)__shfl((int)hi.x, Lx + 16);
            unsigned t3 = (unsigned)__shfl((int)hi.y, Lx + 16);
            uint4x u;
            u[0] = bhi ? t0 : s0;
            u[1] = bhi ? t1 : s1;
            u[2] = bhi ? t2 : s2;
            u[3] = bhi ? t3 : s3;
            hf[h] = __builtin_bit_cast(short8x, u);
        }
        #pragma unroll
        for (int nt = 0; nt < 8; ++nt) {
            acc2[0][nt] = __builtin_amdgcn_mfma_f32_16x16x32_bf16(wf[nt], hf[0], acc2[0][nt], 0, 0, 0);
            acc2[1][nt] = __builtin_amdgcn_mfma_f32_16x16x32_bf16(wf[nt], hf[1], acc2[1][nt], 0, 0, 0);
        }
        if (ks < 3) {
            #pragma unroll
            for (int nt = 0; nt < 8; ++nt) wf[nt] = wn[nt];
        }
    }

    // ---- fused epilogue, in-place in LDS: read x slot, compute, write y to same slot ----
    #pragma unroll
    for (int nt = 0; nt < 8; ++nt) {
        float4 bv = *(const float4*)&b2[nt * 16 + quad * 4];
        #pragma unroll
        for (int h = 0; h < 2; ++h) {
            int rr  = 16 * h + l15;
            int off = rr * 128 + (((nt * 4 + quad) ^ (rr & 7)) << 2);
            float4 xv = *(const float4*)&Xw[off];
            float4x v = acc2[h][nt];
            float4 out;
            {
                float tm = 0.01f * (v[0] + bv.x);
                float tw = 0.01f * (v[1] + bv.y);
                float tm2 = tm * tm, tw2 = tw * tw;
                float ex = fmaf(tm2, fmaf(tm, 0.16666667f, 0.5f), 1.0f + tm);
                float s  = tw * fmaf(tw2, -0.16666667f, 1.0f);
                float c  = fmaf(tw2, -0.5f, 1.0f);
                out.x = ex * fmaf(c, xv.x, -s * xv.y);
                out.y = ex * fmaf(s, xv.x,  c * xv.y);
            }
            {
                float tm = 0.01f * (v[2] + bv.z);
                float tw = 0.01f * (v[3] + bv.w);
                float tm2 = tm * tm, tw2 = tw * tw;
                float ex = fmaf(tm2, fmaf(tm, 0.16666667f, 0.5f), 1.0f + tm);
                float s  = tw * fmaf(tw2, -0.16666667f, 1.0f);
                float c  = fmaf(tw2, -0.5f, 1.0f);
                out.z = ex * fmaf(c, xv.z, -s * xv.w);
                out.w = ex * fmaf(s, xv.z,  c * xv.w);
            }
            *(float4*)&Xw[off] = out;
        }
    }

    // ---- y store: linear LDS read (conflict-free); global dst carries inverse swizzle ----
    #pragma unroll
    for (int c = 0; c < 16; ++c) {
        int r  = c * 2 + (lane >> 5);
        int sp = (lane & 31) ^ (r & 7);
        float4 v = *(const float4*)&Xw[c * 256 + lane * 4];
        float* dst = y + (size_t)(row0 + r) * KDIM + sp * 4;
        *(float4*)dst = v;
    }
}

extern "C" void kernel_launch(void* const* d_in, const int* in_sizes, int n_in,
                              void* d_out, int out_size, void* d_ws, size_t ws_size,
                              hipStream_t stream) {
    const float* x  = (const float*)d_in[0];
    const float* W1 = (const float*)d_in[1];
    const float* b1 = (const float*)d_in[2];
    const float* W2 = (const float*)d_in[3];
    const float* b2 = (const float*)d_in[4];
    float* y = (float*)d_out;

    unsigned short* W1f = (unsigned short*)d_ws;
    unsigned short* W2f = W1f + 128 * 128;

    prep_weights<<<64, 256, 0, stream>>>(W1, W2, W1f, W2f);
    koopman_main<<<BATCH / 128, 256, 0, stream>>>(x, b1, b2, W1f, W2f, y);
}